// Round 6
// baseline (251.591 us; speedup 1.0000x reference)
//
#include <hip/hip_runtime.h>
#include <hip/hip_bf16.h>
#include <math.h>

#define NROWS 8192
#define DDIM  4096
#define NEXP  64
#define KSPLIT 16
#define KCHUNK (DDIM / KSPLIT)   // 256
#define KSTEPS (KCHUNK / 32)     // 8  -- compile-time: allocator pipelines it

typedef __attribute__((ext_vector_type(8))) short bf16x8;
typedef __attribute__((ext_vector_type(4))) float f32x4;

__device__ inline unsigned short bf16_rne(float f) {
    unsigned u = __builtin_bit_cast(unsigned, f);
    u += 0x7FFF + ((u >> 16) & 1);
    return (unsigned short)(u >> 16);
}

// split 8 fp32 -> hi/lo bf16 (x = hi + lo + r, |r| <= 2^-18|x|)
__device__ inline void split8(const float* xf, bf16x8& hi, bf16x8& lo) {
#pragma unroll
    for (int j = 0; j < 8; j++) {
        const unsigned short h = bf16_rne(xf[j]);
        const float hf = __builtin_bit_cast(float, (unsigned)h << 16);
        hi[j] = (short)h;
        lo[j] = (short)bf16_rne(xf[j] - hf);
    }
}

// Preconvert W (64 x 4096 fp32) into MFMA B-fragment-linear bf16 hi/lo:
// frag elem j of lane l, tile t, k-chunk kc = B[k=kc*32+(l>>4)*8+j][n=t*16+(l&15)]
// at ((kc*4+t)*64+l)*8. ~1 MB total -> L2/L3-resident for the GEMM.
// ALSO zeroes the 2 MB logits accumulator (ws is poisoned every iteration,
// and the GEMM accumulates into it with atomics).
__global__ __launch_bounds__(256) void wfrag_kernel(
    const float* __restrict__ w, unsigned short* __restrict__ whi,
    unsigned short* __restrict__ wlo, float* __restrict__ logits)
{
    const int kc = blockIdx.x;            // 0..127
    const int t  = threadIdx.x >> 6;      // n-tile 0..3
    const int l  = threadIdx.x & 63;
    const int e  = t * 16 + (l & 15);
    const int k0 = kc * 32 + ((l >> 4) * 8);
    const float* p = w + (size_t)e * DDIM + k0;
    float xf[8];
    *(float4*)&xf[0] = *(const float4*)p;
    *(float4*)&xf[4] = *(const float4*)(p + 4);
    bf16x8 hi, lo;
    split8(xf, hi, lo);
    const size_t off = ((size_t)(kc * 4 + t) * 64 + l) * 8;
    *(bf16x8*)(whi + off) = hi;
    *(bf16x8*)(wlo + off) = lo;

    // zero logits: 8192*64 floats = 131072 float4; 128 blk * 256 thr * 4 = 131072
    const float4 z = {0.f, 0.f, 0.f, 0.f};
    float4* lz = (float4*)logits;
    const int base = (blockIdx.x * 256 + threadIdx.x) * 4;
#pragma unroll
    for (int j = 0; j < 4; j++) lz[base + j] = z;
}

// GEMM: block = 4 waves; wave = 32 rows (2 m-tiles) x 64 experts.
// x staged through WAVE-PRIVATE LDS (no barriers; R2 lesson: no sync tail).
// Stage via global_load_lds width=16; source pre-swizzled (slot ^= row&7,
// rule 21) so ds_read_b128 fragment reads are bank-uniform. Double-buffered
// 4 KB/wave; counted s_waitcnt vmcnt(8) with sched_barrier(0) pins (T4).
// Epilogue: fire-and-forget HW f32 atomics into the 2 MB logits buffer.
// IDENTICAL to the R5 kernel that passed at 213.7 us.
__global__ __launch_bounds__(256) void gemm_partial_kernel(
    const float* __restrict__ x, const unsigned short* __restrict__ whi,
    const unsigned short* __restrict__ wlo, float* __restrict__ logits)
{
    __shared__ float ldsx[4 * 2 * 1024];   // [wave][buf][32 rows x 32 floats] = 32 KB

    const int tid = threadIdx.x;
    const int wv  = tid >> 6;
    const int l   = tid & 63;
    const int q   = l >> 4;
    const int col = l & 15;
    const int c7  = col & 7;
    const int r0  = blockIdx.x * 128 + wv * 32;
    const int kb  = blockIdx.y * KCHUNK;

    const int slr   = l >> 3;
    const int slotp = l & 7;

    float* ldsw = ldsx + wv * 2048;        // this wave's two 1024-float bufs

    const unsigned short* bhp = whi + ((size_t)(kb / 32) * 4 * 64 + l) * 8;
    const unsigned short* blp = wlo + ((size_t)(kb / 32) * 4 * 64 + l) * 8;

    f32x4 acc[2][4];
#pragma unroll
    for (int m = 0; m < 2; m++)
#pragma unroll
        for (int t = 0; t < 4; t++) acc[m][t] = f32x4{0, 0, 0, 0};

    auto STAGE = [&](int buf, int s) {
#pragma unroll
        for (int g = 0; g < 4; g++) {
            const int lr   = g * 8 + slr;
            const int slot = slotp ^ (lr & 7);
            const float* gp = x + (size_t)(r0 + lr) * DDIM + kb + s * 32 + slot * 4;
            __builtin_amdgcn_global_load_lds(
                (const __attribute__((address_space(1))) void*)gp,
                (__attribute__((address_space(3))) void*)(ldsw + buf * 1024 + g * 256),
                16, 0, 0);
        }
    };

    STAGE(0, 0);
    __builtin_amdgcn_sched_barrier(0);     // pin stage block (wait-count integrity)

    for (int s = 0; s < KSTEPS; s++) {
        const int buf = s & 1;

        // B loads for this step (exactly 8 dwordx4, L2-resident)
        bf16x8 bh[4], bl[4];
        const unsigned short* bhs = bhp + (size_t)s * 4 * 64 * 8;
        const unsigned short* bls = blp + (size_t)s * 4 * 64 * 8;
#pragma unroll
        for (int t = 0; t < 4; t++) {
            bh[t] = *(const bf16x8*)(bhs + (size_t)t * 64 * 8);
            bl[t] = *(const bf16x8*)(bls + (size_t)t * 64 * 8);
        }

        // exactly 8 B-loads issued since stage(buf) -> vmcnt(8) retires the
        // stage (in-order), keeps the B-loads in flight.
        asm volatile("s_waitcnt vmcnt(8)" ::: "memory");
        __builtin_amdgcn_sched_barrier(0); // nothing crosses the wait (rule #18)

        // read this wave's fragments from LDS (swizzled, bank-uniform b128)
        float xr[2][8];
#pragma unroll
        for (int m = 0; m < 2; m++) {
            const float* rb = ldsw + buf * 1024 + (m * 16 + col) * 32;
            const int sp0 = (q * 2) ^ c7;
            *(float4*)&xr[m][0] = *(const float4*)(rb + sp0 * 4);
            *(float4*)&xr[m][4] = *(const float4*)(rb + (sp0 ^ 1) * 4);
        }

        // prefetch next step into the other buffer (wrap at s=7 is a harmless
        // dead re-stage of step 0 -- keeps the wait count uniform)
        STAGE(buf ^ 1, (s + 1) & 7);
        __builtin_amdgcn_sched_barrier(0);

        bf16x8 ah[2], al[2];
        split8(xr[0], ah[0], al[0]);
        split8(xr[1], ah[1], al[1]);
#pragma unroll
        for (int m = 0; m < 2; m++)
#pragma unroll
            for (int t = 0; t < 4; t++) {
                acc[m][t] = __builtin_amdgcn_mfma_f32_16x16x32_bf16(ah[m], bh[t], acc[m][t], 0, 0, 0);
                acc[m][t] = __builtin_amdgcn_mfma_f32_16x16x32_bf16(ah[m], bl[t], acc[m][t], 0, 0, 0);
                acc[m][t] = __builtin_amdgcn_mfma_f32_16x16x32_bf16(al[m], bh[t], acc[m][t], 0, 0, 0);
            }
    }

    // C/D: row = q*4 + r, col = l&15  (m89-verified mapping)
#pragma unroll
    for (int m = 0; m < 2; m++)
#pragma unroll
        for (int t = 0; t < 4; t++)
#pragma unroll
            for (int r = 0; r < 4; r++)
                unsafeAtomicAdd(
                    &logits[(size_t)(r0 + m * 16 + q * 4 + r) * NEXP + t * 16 + col],
                    acc[m][t][r]);
}

// One wave per row: load logit, sigmoid, +bias, top-2 (tie -> lower index),
// normalize. out: [weights 2N][indices-as-float 2N][scores 64N]
__global__ __launch_bounds__(256) void gate_topk_kernel(
    const float* __restrict__ logits, const float* __restrict__ bias,
    float* __restrict__ out)
{
    const int tid = threadIdx.x;
    const int e   = tid & 63;
    const int row = blockIdx.x * 4 + (tid >> 6);
    const size_t idx = (size_t)row * NEXP + e;

    const float be    = bias[e];        // issue before logit load
    const float logit = logits[idx];
    const float score = 1.0f / (1.0f + expf(-logit));
    out[(size_t)4 * NROWS + idx] = score;           // scores

    const float biased = score + be;

    float v = biased; int bi = e;
#pragma unroll
    for (int off = 32; off; off >>= 1) {
        const float ov = __shfl_xor(v, off);
        const int   oi = __shfl_xor(bi, off);
        if (ov > v || (ov == v && oi < bi)) { v = ov; bi = oi; }
    }
    const int i1 = bi;

    float v2 = (e == i1) ? -INFINITY : biased;
    int bi2 = e;
#pragma unroll
    for (int off = 32; off; off >>= 1) {
        const float ov = __shfl_xor(v2, off);
        const int   oi = __shfl_xor(bi2, off);
        if (ov > v2 || (ov == v2 && oi < bi2)) { v2 = ov; bi2 = oi; }
    }
    const int i2 = bi2;

    const float s1 = __shfl(score, i1);
    const float s2 = __shfl(score, i2);
    if (e == 0) {
        const float inv = 1.0f / (s1 + s2);
        out[(size_t)row * 2 + 0] = s1 * inv;
        out[(size_t)row * 2 + 1] = s2 * inv;
        out[(size_t)2 * NROWS + row * 2 + 0] = (float)i1;
        out[(size_t)2 * NROWS + row * 2 + 1] = (float)i2;
    }
}

extern "C" void kernel_launch(void* const* d_in, const int* in_sizes, int n_in,
                              void* d_out, int out_size, void* d_ws, size_t ws_size,
                              hipStream_t stream)
{
    const float* x    = (const float*)d_in[0];
    const float* w    = (const float*)d_in[1];
    const float* bias = (const float*)d_in[2];
    float* out  = (float*)d_out;

    float* logits = (float*)d_ws;                               // 2 MB
    const size_t logits_bytes = (size_t)NROWS * NEXP * 4;
    unsigned short* whi = (unsigned short*)((char*)d_ws + logits_bytes);  // 512 KB
    unsigned short* wlo = whi + (size_t)NEXP * DDIM;                      // 512 KB
    float* logits2 = (float*)(wlo + (size_t)NEXP * DDIM);       // 2 MB scratch (probe)

    wfrag_kernel<<<DDIM / 32, 256, 0, stream>>>(w, whi, wlo, logits);
    dim3 g1(NROWS / 128, KSPLIT);
    gemm_partial_kernel<<<g1, 256, 0, stream>>>(x, whi, wlo, logits);
    gate_topk_kernel<<<NROWS / 4, 256, 0, stream>>>(logits, bias, out);

    // ---- MEASUREMENT PROBE (R6): exact duplicate GEMM into scratch ----
    // Real pipeline above is bit-identical to R5 (213.7 us). The dur_us
    // delta vs R5 directly measures the (L3-warm) GEMM duration, which the
    // rocprof top-5 cannot show (five ~77 us poison fills outrank it).
    // Probe output is never read; atomics onto poisoned scratch are benign.
    gemm_partial_kernel<<<g1, 256, 0, stream>>>(x, whi, wlo, logits2);
}

// Round 7
// 220.882 us; speedup vs baseline: 1.1390x; 1.1390x over previous
//
#include <hip/hip_runtime.h>
#include <hip/hip_bf16.h>
#include <math.h>

#define NROWS 8192
#define DDIM  4096
#define NEXP  64
#define KSPLIT 16
#define KCHUNK (DDIM / KSPLIT)   // 256
#define KSTEPS (KCHUNK / 32)     // 8  -- compile-time: fully unrolled below

typedef __attribute__((ext_vector_type(8))) short bf16x8;
typedef __attribute__((ext_vector_type(4))) float f32x4;

__device__ inline unsigned short bf16_rne(float f) {
    unsigned u = __builtin_bit_cast(unsigned, f);
    u += 0x7FFF + ((u >> 16) & 1);
    return (unsigned short)(u >> 16);
}

// split 8 fp32 -> hi/lo bf16 (x = hi + lo + r, |r| <= 2^-18|x|)
__device__ inline void split8(const float* xf, bf16x8& hi, bf16x8& lo) {
#pragma unroll
    for (int j = 0; j < 8; j++) {
        const unsigned short h = bf16_rne(xf[j]);
        const float hf = __builtin_bit_cast(float, (unsigned)h << 16);
        hi[j] = (short)h;
        lo[j] = (short)bf16_rne(xf[j] - hf);
    }
}

// Preconvert W (64 x 4096 fp32) into MFMA B-fragment-linear bf16 hi/lo:
// frag elem j of lane l, tile t, k-chunk kc = B[k=kc*32+(l>>4)*8+j][n=t*16+(l&15)]
// at ((kc*4+t)*64+l)*8. ~1 MB total -> L2/L3-resident for the GEMM.
// ALSO zeroes the 2 MB logits accumulator (ws is poisoned every iteration,
// and the GEMM accumulates into it with atomics).
__global__ __launch_bounds__(256) void wfrag_kernel(
    const float* __restrict__ w, unsigned short* __restrict__ whi,
    unsigned short* __restrict__ wlo, float* __restrict__ logits)
{
    const int kc = blockIdx.x;            // 0..127
    const int t  = threadIdx.x >> 6;      // n-tile 0..3
    const int l  = threadIdx.x & 63;
    const int e  = t * 16 + (l & 15);
    const int k0 = kc * 32 + ((l >> 4) * 8);
    const float* p = w + (size_t)e * DDIM + k0;
    float xf[8];
    *(float4*)&xf[0] = *(const float4*)p;
    *(float4*)&xf[4] = *(const float4*)(p + 4);
    bf16x8 hi, lo;
    split8(xf, hi, lo);
    const size_t off = ((size_t)(kc * 4 + t) * 64 + l) * 8;
    *(bf16x8*)(whi + off) = hi;
    *(bf16x8*)(wlo + off) = lo;

    // zero logits: 8192*64 floats = 131072 float4; 128 blk * 256 thr * 4 = 131072
    const float4 z = {0.f, 0.f, 0.f, 0.f};
    float4* lz = (float4*)logits;
    const int base = (blockIdx.x * 256 + threadIdx.x) * 4;
#pragma unroll
    for (int j = 0; j < 4; j++) lz[base + j] = z;
}

// GEMM: block = 4 waves; wave = 32 rows (2 m-tiles) x 64 experts.
// R6 probe measured: warm GEMM = 38 us (no HBM), cold = ~70 us -> the 134 MB
// x-read was ~100% latency-exposed (1-step prefetch = ~400 cyc cover vs
// ~900 cyc HBM latency). Fix: DEEP PIPELINE.
//   - x: TRIPLE-buffered wave-private LDS; stage(s) issued 2 iterations
//     before its wait (~1000 cyc cover). 48 KB/block -> 3 blocks/CU.
//   - B: register double-buffer; B(s+1) loaded during iter s, so MFMA
//     never waits on same-iteration loads (L2/L3 ~200-500 cyc covered).
//   - ONE counted wait/iter. vmcnt ledger (in-order retirement), verified
//     by simulation: prologue B0(8),S0,S1,S2(12)=20 out. iter0: vmcnt(8)
//     retires B0,S0. iters>=1: vmcnt(4) retires S(s),B(s) (S(s+1..2)
//     forced in the drag chain exactly on schedule), leaves newest 4.
//     Per-iter issues: B(s+1)(8) then S(s+3)(4) -- uniform, tail wrapped
//     to dead re-loads so counts never change (R5-validated trick).
// Source pre-swizzle (slot ^= row&7, rule 21) unchanged; ds_read after the
// wait reads only retired buffers (m97 precedent: compiler does NOT
// force-drain LDS-DMA before unrelated ds_read). Full unroll keeps all
// buffer indices compile-time (rule #20). Epilogue unchanged: fire-and-
// forget f32 atomics, no sync tail (R2 lesson).
__global__ __launch_bounds__(256) void gemm_partial_kernel(
    const float* __restrict__ x, const unsigned short* __restrict__ whi,
    const unsigned short* __restrict__ wlo, float* __restrict__ logits)
{
    __shared__ float ldsx[4 * 3 * 1024];   // [wave][3 bufs][32 rows x 32 f] = 48 KB

    const int tid = threadIdx.x;
    const int wv  = tid >> 6;
    const int l   = tid & 63;
    const int q   = l >> 4;
    const int col = l & 15;
    const int c7  = col & 7;
    const int r0  = blockIdx.x * 128 + wv * 32;
    const int kb  = blockIdx.y * KCHUNK;

    const int slr   = l >> 3;
    const int slotp = l & 7;

    float* ldsw = ldsx + wv * 3072;        // this wave's three 1024-float bufs

    const unsigned short* bhp = whi + ((size_t)(kb / 32) * 4 * 64 + l) * 8;
    const unsigned short* blp = wlo + ((size_t)(kb / 32) * 4 * 64 + l) * 8;

    f32x4 acc[2][4];
#pragma unroll
    for (int m = 0; m < 2; m++)
#pragma unroll
        for (int t = 0; t < 4; t++) acc[m][t] = f32x4{0, 0, 0, 0};

    bf16x8 bh[2][4], bl[2][4];             // B register double-buffer (64 VGPR)

    auto STAGE = [&](int bufi, int s) {    // 4 x global_load_lds dwordx4
#pragma unroll
        for (int g = 0; g < 4; g++) {
            const int lr   = g * 8 + slr;
            const int slot = slotp ^ (lr & 7);
            const float* gp = x + (size_t)(r0 + lr) * DDIM + kb + s * 32 + slot * 4;
            __builtin_amdgcn_global_load_lds(
                (const __attribute__((address_space(1))) void*)gp,
                (__attribute__((address_space(3))) void*)(ldsw + bufi * 1024 + g * 256),
                16, 0, 0);
        }
    };

    auto LOADB = [&](int rb, int s) {      // 8 x dwordx4 (L2-resident)
        const unsigned short* bhs = bhp + (size_t)s * 4 * 64 * 8;
        const unsigned short* bls = blp + (size_t)s * 4 * 64 * 8;
#pragma unroll
        for (int t = 0; t < 4; t++) {
            bh[rb][t] = *(const bf16x8*)(bhs + (size_t)t * 64 * 8);
            bl[rb][t] = *(const bf16x8*)(bls + (size_t)t * 64 * 8);
        }
    };

    // prologue: B0 first (so its retirement doesn't drag later stages),
    // then 3 stages. Outstanding: 8 + 12 = 20.
    LOADB(0, 0);
    STAGE(0, 0);
    STAGE(1, 1);
    STAGE(2, 2);
    __builtin_amdgcn_sched_barrier(0);

#pragma unroll
    for (int s = 0; s < KSTEPS; s++) {
        const int rb = s & 1;

        // (a) the ONE wait: S(s) and B(s) retired; newest stage stays in flight
        if (s == 0) asm volatile("s_waitcnt vmcnt(8)" ::: "memory");
        else        asm volatile("s_waitcnt vmcnt(4)" ::: "memory");
        __builtin_amdgcn_sched_barrier(0);

        // (c) next B into the other reg buffer -- in flight during LDS reads
        LOADB(rb ^ 1, (s + 1) & 7);
        __builtin_amdgcn_sched_barrier(0);

        // (b) read this wave's fragments from LDS buf s%3 (swizzled b128)
        float xr[2][8];
#pragma unroll
        for (int m = 0; m < 2; m++) {
            const float* rbp = ldsw + (s % 3) * 1024 + (m * 16 + col) * 32;
            const int sp0 = (q * 2) ^ c7;
            *(float4*)&xr[m][0] = *(const float4*)(rbp + sp0 * 4);
            *(float4*)&xr[m][4] = *(const float4*)(rbp + (sp0 ^ 1) * 4);
        }

        bf16x8 ah[2], al[2];
        split8(xr[0], ah[0], al[0]);       // forces lgkmcnt: buf s%3 fully read
        split8(xr[1], ah[1], al[1]);

        // (d) restage the just-consumed buffer with step s+3 (dead wrap at tail)
        STAGE(s % 3, (s + 3) & 7);
        __builtin_amdgcn_sched_barrier(0);

        // (e) MFMA on registers only -- no vmem wait inside
#pragma unroll
        for (int m = 0; m < 2; m++)
#pragma unroll
            for (int t = 0; t < 4; t++) {
                acc[m][t] = __builtin_amdgcn_mfma_f32_16x16x32_bf16(ah[m], bh[rb][t], acc[m][t], 0, 0, 0);
                acc[m][t] = __builtin_amdgcn_mfma_f32_16x16x32_bf16(ah[m], bl[rb][t], acc[m][t], 0, 0, 0);
                acc[m][t] = __builtin_amdgcn_mfma_f32_16x16x32_bf16(al[m], bh[rb][t], acc[m][t], 0, 0, 0);
            }
    }

    // C/D: row = q*4 + r, col = l&15  (m89-verified mapping)
    // Fire-and-forget HW f32 atomics; 16 lanes (col) contiguous per (m,t,r).
#pragma unroll
    for (int m = 0; m < 2; m++)
#pragma unroll
        for (int t = 0; t < 4; t++)
#pragma unroll
            for (int r = 0; r < 4; r++)
                unsafeAtomicAdd(
                    &logits[(size_t)(r0 + m * 16 + q * 4 + r) * NEXP + t * 16 + col],
                    acc[m][t][r]);
}

// One wave per row: load logit, sigmoid, +bias, top-2 (tie -> lower index),
// normalize. Kernel boundary after the GEMM provides cross-XCD coherence for
// the plain logits loads (verified passing R1/R3/R5).
// out: [weights 2N][indices-as-float 2N][scores 64N]
__global__ __launch_bounds__(256) void gate_topk_kernel(
    const float* __restrict__ logits, const float* __restrict__ bias,
    float* __restrict__ out)
{
    const int tid = threadIdx.x;
    const int e   = tid & 63;
    const int row = blockIdx.x * 4 + (tid >> 6);
    const size_t idx = (size_t)row * NEXP + e;

    const float be    = bias[e];        // issue before logit load
    const float logit = logits[idx];
    const float score = 1.0f / (1.0f + expf(-logit));
    out[(size_t)4 * NROWS + idx] = score;           // scores

    const float biased = score + be;

    float v = biased; int bi = e;
#pragma unroll
    for (int off = 32; off; off >>= 1) {
        const float ov = __shfl_xor(v, off);
        const int   oi = __shfl_xor(bi, off);
        if (ov > v || (ov == v && oi < bi)) { v = ov; bi = oi; }
    }
    const int i1 = bi;

    float v2 = (e == i1) ? -INFINITY : biased;
    int bi2 = e;
#pragma unroll
    for (int off = 32; off; off >>= 1) {
        const float ov = __shfl_xor(v2, off);
        const int   oi = __shfl_xor(bi2, off);
        if (ov > v2 || (ov == v2 && oi < bi2)) { v2 = ov; bi2 = oi; }
    }
    const int i2 = bi2;

    const float s1 = __shfl(score, i1);
    const float s2 = __shfl(score, i2);
    if (e == 0) {
        const float inv = 1.0f / (s1 + s2);
        out[(size_t)row * 2 + 0] = s1 * inv;
        out[(size_t)row * 2 + 1] = s2 * inv;
        out[(size_t)2 * NROWS + row * 2 + 0] = (float)i1;
        out[(size_t)2 * NROWS + row * 2 + 1] = (float)i2;
    }
}

extern "C" void kernel_launch(void* const* d_in, const int* in_sizes, int n_in,
                              void* d_out, int out_size, void* d_ws, size_t ws_size,
                              hipStream_t stream)
{
    const float* x    = (const float*)d_in[0];
    const float* w    = (const float*)d_in[1];
    const float* bias = (const float*)d_in[2];
    float* out  = (float*)d_out;

    float* logits = (float*)d_ws;                               // 2 MB
    const size_t logits_bytes = (size_t)NROWS * NEXP * 4;
    unsigned short* whi = (unsigned short*)((char*)d_ws + logits_bytes);  // 512 KB
    unsigned short* wlo = whi + (size_t)NEXP * DDIM;                      // 512 KB

    wfrag_kernel<<<DDIM / 32, 256, 0, stream>>>(w, whi, wlo, logits);
    dim3 g1(NROWS / 128, KSPLIT);
    gemm_partial_kernel<<<g1, 256, 0, stream>>>(x, whi, wlo, logits);
    gate_topk_kernel<<<NROWS / 4, 256, 0, stream>>>(logits, bias, out);
}

// Round 8
// 211.834 us; speedup vs baseline: 1.1877x; 1.0427x over previous
//
#include <hip/hip_runtime.h>
#include <hip/hip_bf16.h>
#include <math.h>

#define NROWS 8192
#define DDIM  4096
#define NEXP  64
#define KSPLIT 4                 // K split ACROSS blocks (kh); waves split it further
#define KCHUNK (DDIM / KSPLIT)   // 1024 per block; 256 per wave
#define KSTEPS 8                 // per-wave k32 steps (256/32)

typedef __attribute__((ext_vector_type(8))) short bf16x8;
typedef __attribute__((ext_vector_type(4))) float f32x4;

__device__ inline unsigned short bf16_rne(float f) {
    unsigned u = __builtin_bit_cast(unsigned, f);
    u += 0x7FFF + ((u >> 16) & 1);
    return (unsigned short)(u >> 16);
}

// split 8 fp32 -> hi/lo bf16 (x = hi + lo + r, |r| <= 2^-18|x|)
__device__ inline void split8(const float* xf, bf16x8& hi, bf16x8& lo) {
#pragma unroll
    for (int j = 0; j < 8; j++) {
        const unsigned short h = bf16_rne(xf[j]);
        const float hf = __builtin_bit_cast(float, (unsigned)h << 16);
        hi[j] = (short)h;
        lo[j] = (short)bf16_rne(xf[j] - hf);
    }
}

// Preconvert W (64 x 4096 fp32) into MFMA B-fragment-linear bf16 hi/lo:
// frag elem j of lane l, tile t, k-chunk kc = B[k=kc*32+(l>>4)*8+j][n=t*16+(l&15)]
// at ((kc*4+t)*64+l)*8. ~1 MB total -> L2/L3-resident for the GEMM.
__global__ __launch_bounds__(256) void wfrag_kernel(
    const float* __restrict__ w, unsigned short* __restrict__ whi,
    unsigned short* __restrict__ wlo)
{
    const int kc = blockIdx.x;            // 0..127
    const int t  = threadIdx.x >> 6;      // n-tile 0..3
    const int l  = threadIdx.x & 63;
    const int e  = t * 16 + (l & 15);
    const int k0 = kc * 32 + ((l >> 4) * 8);
    const float* p = w + (size_t)e * DDIM + k0;
    float xf[8];
    *(float4*)&xf[0] = *(const float4*)p;
    *(float4*)&xf[4] = *(const float4*)(p + 4);
    bf16x8 hi, lo;
    split8(xf, hi, lo);
    const size_t off = ((size_t)(kc * 4 + t) * 64 + l) * 8;
    *(bf16x8*)(whi + off) = hi;
    *(bf16x8*)(wlo + off) = lo;
}

// GEMM, atomic-free split-K. R6 probe: warm GEMM = 38 us vs ~8 us issue
// model; R0->R1 showed the 8.4M-RMW atomic epilogue costs nearly as much
// as a 64 MB part[] round trip (~15-20 us). Fix: in-block split-K.
// Block = 4 waves on the SAME 32 rows; wave wv covers k-chunk
// [kh*1024 + wv*256, +256). Inner loop bit-identical to the verified R5
// loop (double-buffered wave-private LDS staging via global_load_lds w=16,
// pre-swizzled source slot ^= row&7 (rule 21), counted s_waitcnt vmcnt(8)
// + sched_barrier pins). R7's deeper pipeline regressed -- reverted.
// Tail (replaces ALL atomics): vmcnt(0) drain (LDS-DMA alias safety),
// each wave writes its 32x64 partial into its own staging region
// (row_local*64+exp), one __syncthreads, then 256 threads sum the 4
// wave-partials (8 values each, float4) and store plain coalesced
// dwordx4 to part[kh]. Branchless, shuffle-free tail to dodge the R2
// VGPR-squeeze. part = 4 x 2 MB; gate_topk sums 4 partials.
__global__ __launch_bounds__(256) void gemm_partial_kernel(
    const float* __restrict__ x, const unsigned short* __restrict__ whi,
    const unsigned short* __restrict__ wlo, float* __restrict__ part)
{
    __shared__ float ldsx[4 * 2 * 1024];   // 32 KB staging; aliased for reduce

    const int tid = threadIdx.x;
    const int wv  = tid >> 6;
    const int l   = tid & 63;
    const int q   = l >> 4;
    const int col = l & 15;
    const int c7  = col & 7;
    const int r0  = blockIdx.x * 32;       // 32 rows per block now
    const int kh  = blockIdx.y;
    const int kb  = kh * KCHUNK + wv * 256;  // this wave's private k-range

    const int slr   = l >> 3;
    const int slotp = l & 7;

    float* ldsw = ldsx + wv * 2048;        // this wave's two 1024-float bufs

    const unsigned short* bhp = whi + ((size_t)(kb / 32) * 4 * 64 + l) * 8;
    const unsigned short* blp = wlo + ((size_t)(kb / 32) * 4 * 64 + l) * 8;

    f32x4 acc[2][4];
#pragma unroll
    for (int m = 0; m < 2; m++)
#pragma unroll
        for (int t = 0; t < 4; t++) acc[m][t] = f32x4{0, 0, 0, 0};

    auto STAGE = [&](int buf, int s) {     // 4 x global_load_lds dwordx4
#pragma unroll
        for (int g = 0; g < 4; g++) {
            const int lr   = g * 8 + slr;
            const int slot = slotp ^ (lr & 7);
            const float* gp = x + (size_t)(r0 + lr) * DDIM + kb + s * 32 + slot * 4;
            __builtin_amdgcn_global_load_lds(
                (const __attribute__((address_space(1))) void*)gp,
                (__attribute__((address_space(3))) void*)(ldsw + buf * 1024 + g * 256),
                16, 0, 0);
        }
    };

    STAGE(0, 0);
    __builtin_amdgcn_sched_barrier(0);     // pin stage block (wait-count integrity)

#pragma unroll
    for (int s = 0; s < KSTEPS; s++) {
        const int buf = s & 1;

        // B loads for this step (exactly 8 dwordx4, L2-resident)
        bf16x8 bh[4], bl[4];
        const unsigned short* bhs = bhp + (size_t)s * 4 * 64 * 8;
        const unsigned short* bls = blp + (size_t)s * 4 * 64 * 8;
#pragma unroll
        for (int t = 0; t < 4; t++) {
            bh[t] = *(const bf16x8*)(bhs + (size_t)t * 64 * 8);
            bl[t] = *(const bf16x8*)(bls + (size_t)t * 64 * 8);
        }

        // exactly 8 B-loads issued since stage(buf) -> vmcnt(8) retires the
        // stage (in-order), keeps the B-loads in flight.
        asm volatile("s_waitcnt vmcnt(8)" ::: "memory");
        __builtin_amdgcn_sched_barrier(0); // nothing crosses the wait (rule #18)

        // read this wave's fragments from LDS (swizzled, bank-uniform b128)
        float xr[2][8];
#pragma unroll
        for (int m = 0; m < 2; m++) {
            const float* rbp = ldsw + buf * 1024 + (m * 16 + col) * 32;
            const int sp0 = (q * 2) ^ c7;
            *(float4*)&xr[m][0] = *(const float4*)(rbp + sp0 * 4);
            *(float4*)&xr[m][4] = *(const float4*)(rbp + (sp0 ^ 1) * 4);
        }

        // prefetch next step (skipped on last iter -- compile-time; later
        // waits unaffected, tail drains via vmcnt(0) below)
        if (s + 1 < KSTEPS) STAGE(buf ^ 1, s + 1);
        __builtin_amdgcn_sched_barrier(0);

        bf16x8 ah[2], al[2];
        split8(xr[0], ah[0], al[0]);
        split8(xr[1], ah[1], al[1]);
#pragma unroll
        for (int m = 0; m < 2; m++)
#pragma unroll
            for (int t = 0; t < 4; t++) {
                acc[m][t] = __builtin_amdgcn_mfma_f32_16x16x32_bf16(ah[m], bh[t], acc[m][t], 0, 0, 0);
                acc[m][t] = __builtin_amdgcn_mfma_f32_16x16x32_bf16(ah[m], bl[t], acc[m][t], 0, 0, 0);
                acc[m][t] = __builtin_amdgcn_mfma_f32_16x16x32_bf16(al[m], bh[t], acc[m][t], 0, 0, 0);
            }
    }

    // ---- atomic-free tail: cross-wave K reduction in LDS ----
    asm volatile("s_waitcnt vmcnt(0)" ::: "memory");   // all LDS-DMA landed (alias safety)
    __builtin_amdgcn_sched_barrier(0);

    // C/D: row_local = m*16 + q*4 + r, exp = t*16 + col (m89-verified mapping)
#pragma unroll
    for (int m = 0; m < 2; m++)
#pragma unroll
        for (int t = 0; t < 4; t++)
#pragma unroll
            for (int r = 0; r < 4; r++)
                ldsx[wv * 2048 + (m * 16 + q * 4 + r) * 64 + t * 16 + col] = acc[m][t][r];

    __syncthreads();

    // 256 threads x 8 values: sum the 4 wave-partials, store coalesced.
    const f32x4* lp = (const f32x4*)ldsx;   // wave region stride = 512 f32x4
    const f32x4 s0 = lp[tid * 2]     + lp[512 + tid * 2]     + lp[1024 + tid * 2]     + lp[1536 + tid * 2];
    const f32x4 s1 = lp[tid * 2 + 1] + lp[512 + tid * 2 + 1] + lp[1024 + tid * 2 + 1] + lp[1536 + tid * 2 + 1];
    float* po = part + (size_t)kh * NROWS * NEXP + (size_t)r0 * NEXP + tid * 8;
    *(f32x4*)po       = s0;
    *(f32x4*)(po + 4) = s1;
}

// One wave per row: sum 4 split-K partials, sigmoid, +bias, top-2 (tie ->
// lower index), normalize. Kernel boundary provides cross-XCD visibility of
// part (plain stores -> plain loads, verified pattern from R0).
// out: [weights 2N][indices-as-float 2N][scores 64N]
__global__ __launch_bounds__(256) void gate_topk_kernel(
    const float* __restrict__ part, const float* __restrict__ bias,
    float* __restrict__ out)
{
    const int tid = threadIdx.x;
    const int e   = tid & 63;
    const int row = blockIdx.x * 4 + (tid >> 6);
    const size_t idx = (size_t)row * NEXP + e;

    const float be = bias[e];           // issue before partial loads
    float logit = 0.f;
#pragma unroll
    for (int s = 0; s < KSPLIT; s++)
        logit += part[(size_t)s * NROWS * NEXP + idx];
    const float score = 1.0f / (1.0f + expf(-logit));
    out[(size_t)4 * NROWS + idx] = score;           // scores

    const float biased = score + be;

    float v = biased; int bi = e;
#pragma unroll
    for (int off = 32; off; off >>= 1) {
        const float ov = __shfl_xor(v, off);
        const int   oi = __shfl_xor(bi, off);
        if (ov > v || (ov == v && oi < bi)) { v = ov; bi = oi; }
    }
    const int i1 = bi;

    float v2 = (e == i1) ? -INFINITY : biased;
    int bi2 = e;
#pragma unroll
    for (int off = 32; off; off >>= 1) {
        const float ov = __shfl_xor(v2, off);
        const int   oi = __shfl_xor(bi2, off);
        if (ov > v2 || (ov == v2 && oi < bi2)) { v2 = ov; bi2 = oi; }
    }
    const int i2 = bi2;

    const float s1 = __shfl(score, i1);
    const float s2 = __shfl(score, i2);
    if (e == 0) {
        const float inv = 1.0f / (s1 + s2);
        out[(size_t)row * 2 + 0] = s1 * inv;
        out[(size_t)row * 2 + 1] = s2 * inv;
        out[(size_t)2 * NROWS + row * 2 + 0] = (float)i1;
        out[(size_t)2 * NROWS + row * 2 + 1] = (float)i2;
    }
}

extern "C" void kernel_launch(void* const* d_in, const int* in_sizes, int n_in,
                              void* d_out, int out_size, void* d_ws, size_t ws_size,
                              hipStream_t stream)
{
    const float* x    = (const float*)d_in[0];
    const float* w    = (const float*)d_in[1];
    const float* bias = (const float*)d_in[2];
    float* out  = (float*)d_out;

    float* part = (float*)d_ws;                                 // 4 x 2 MB
    const size_t part_bytes = (size_t)KSPLIT * NROWS * NEXP * 4;
    unsigned short* whi = (unsigned short*)((char*)d_ws + part_bytes);  // 512 KB
    unsigned short* wlo = whi + (size_t)NEXP * DDIM;                    // 512 KB

    wfrag_kernel<<<DDIM / 32, 256, 0, stream>>>(w, whi, wlo);
    dim3 g1(NROWS / 32, KSPLIT);                                // (256, 4) = 1024 blocks
    gemm_partial_kernel<<<g1, 256, 0, stream>>>(x, whi, wlo, part);
    gate_topk_kernel<<<NROWS / 4, 256, 0, stream>>>(part, bias, out);
}

// Round 10
// 209.330 us; speedup vs baseline: 1.2019x; 1.0120x over previous
//
#include <hip/hip_runtime.h>
#include <hip/hip_bf16.h>
#include <math.h>

#define NROWS 8192
#define DDIM  4096
#define NEXP  64
#define KSPLIT 8                 // K split ACROSS blocks (kh); waves split it further
#define KCHUNK (DDIM / KSPLIT)   // 512 per block; 128 per wave
#define KSTEPS 4                 // per-wave k32 steps (128/32)

typedef __attribute__((ext_vector_type(8))) short bf16x8;
typedef __attribute__((ext_vector_type(4))) float f32x4;

__device__ inline unsigned short bf16_rne(float f) {
    unsigned u = __builtin_bit_cast(unsigned, f);
    u += 0x7FFF + ((u >> 16) & 1);
    return (unsigned short)(u >> 16);
}

// split 8 fp32 -> hi/lo bf16 (x = hi + lo + r, |r| <= 2^-18|x|)
__device__ inline void split8(const float* xf, bf16x8& hi, bf16x8& lo) {
#pragma unroll
    for (int j = 0; j < 8; j++) {
        const unsigned short h = bf16_rne(xf[j]);
        const float hf = __builtin_bit_cast(float, (unsigned)h << 16);
        hi[j] = (short)h;
        lo[j] = (short)bf16_rne(xf[j] - hf);
    }
}

// Preconvert W (64 x 4096 fp32) into MFMA B-fragment-linear bf16 hi/lo:
// frag elem j of lane l, tile t, k-chunk kc = B[k=kc*32+(l>>4)*8+j][n=t*16+(l&15)]
// at ((kc*4+t)*64+l)*8. ~1 MB total -> L2/L3-resident for the GEMM.
__global__ __launch_bounds__(256) void wfrag_kernel(
    const float* __restrict__ w, unsigned short* __restrict__ whi,
    unsigned short* __restrict__ wlo)
{
    const int kc = blockIdx.x;            // 0..127
    const int t  = threadIdx.x >> 6;      // n-tile 0..3
    const int l  = threadIdx.x & 63;
    const int e  = t * 16 + (l & 15);
    const int k0 = kc * 32 + ((l >> 4) * 8);
    const float* p = w + (size_t)e * DDIM + k0;
    float xf[8];
    *(float4*)&xf[0] = *(const float4*)p;
    *(float4*)&xf[4] = *(const float4*)(p + 4);
    bf16x8 hi, lo;
    split8(xf, hi, lo);
    const size_t off = ((size_t)(kc * 4 + t) * 64 + l) * 8;
    *(bf16x8*)(whi + off) = hi;
    *(bf16x8*)(wlo + off) = lo;
}

// GEMM, atomic-free split-K. Session ledger: 5 structural variants all land
// 211-221 us; fixed harness cost ~138 us; warm GEMM 38 us vs ~5 us issue
// model -> binding constraint is latency-hiding at the OCCUPANCY level.
// All prior variants ran 16 waves/CU (4 blk x 4 wv, LDS-capped 32 KB/blk).
// This round (R9 re-run; R9 was an infra flake -- full hazard audit found
// no fault path): KSPLIT 4->8. Same 32 KB/block -> 5 blocks/CU resident =
// 20 waves/CU (+25% TLP); grid 2048 blocks; per-wave work 4 k-steps.
// Inner loop BIT-IDENTICAL to the verified R8 loop (double-buffered
// wave-private LDS staging via global_load_lds w=16, pre-swizzled source
// slot ^= row&7 (rule 21), counted s_waitcnt vmcnt(8) + sched_barrier
// pins, no cross-wave sync in the main loop).
// Tail: vmcnt(0) drain, wave partials to LDS, one __syncthreads, 4-way
// sum, plain coalesced dwordx4 stores to part[kh] (atomic-free, R8).
__global__ __launch_bounds__(256) void gemm_partial_kernel(
    const float* __restrict__ x, const unsigned short* __restrict__ whi,
    const unsigned short* __restrict__ wlo, float* __restrict__ part)
{
    __shared__ float ldsx[4 * 2 * 1024];   // 32 KB staging; aliased for reduce

    const int tid = threadIdx.x;
    const int wv  = tid >> 6;
    const int l   = tid & 63;
    const int q   = l >> 4;
    const int col = l & 15;
    const int c7  = col & 7;
    const int r0  = blockIdx.x * 32;       // 32 rows per block
    const int kh  = blockIdx.y;
    const int kb  = kh * KCHUNK + wv * 128;  // this wave's private 128-k range

    const int slr   = l >> 3;
    const int slotp = l & 7;

    float* ldsw = ldsx + wv * 2048;        // this wave's two 1024-float bufs

    const unsigned short* bhp = whi + ((size_t)(kb / 32) * 4 * 64 + l) * 8;
    const unsigned short* blp = wlo + ((size_t)(kb / 32) * 4 * 64 + l) * 8;

    f32x4 acc[2][4];
#pragma unroll
    for (int m = 0; m < 2; m++)
#pragma unroll
        for (int t = 0; t < 4; t++) acc[m][t] = f32x4{0, 0, 0, 0};

    auto STAGE = [&](int buf, int s) {     // 4 x global_load_lds dwordx4
#pragma unroll
        for (int g = 0; g < 4; g++) {
            const int lr   = g * 8 + slr;
            const int slot = slotp ^ (lr & 7);
            const float* gp = x + (size_t)(r0 + lr) * DDIM + kb + s * 32 + slot * 4;
            __builtin_amdgcn_global_load_lds(
                (const __attribute__((address_space(1))) void*)gp,
                (__attribute__((address_space(3))) void*)(ldsw + buf * 1024 + g * 256),
                16, 0, 0);
        }
    };

    STAGE(0, 0);
    __builtin_amdgcn_sched_barrier(0);     // pin stage block (wait-count integrity)

#pragma unroll
    for (int s = 0; s < KSTEPS; s++) {
        const int buf = s & 1;

        // B loads for this step (exactly 8 dwordx4, L2-resident)
        bf16x8 bh[4], bl[4];
        const unsigned short* bhs = bhp + (size_t)s * 4 * 64 * 8;
        const unsigned short* bls = blp + (size_t)s * 4 * 64 * 8;
#pragma unroll
        for (int t = 0; t < 4; t++) {
            bh[t] = *(const bf16x8*)(bhs + (size_t)t * 64 * 8);
            bl[t] = *(const bf16x8*)(bls + (size_t)t * 64 * 8);
        }

        // exactly 8 B-loads issued since stage(buf) -> vmcnt(8) retires the
        // stage (in-order), keeps the B-loads in flight.
        asm volatile("s_waitcnt vmcnt(8)" ::: "memory");
        __builtin_amdgcn_sched_barrier(0); // nothing crosses the wait (rule #18)

        // read this wave's fragments from LDS (swizzled, bank-uniform b128)
        float xr[2][8];
#pragma unroll
        for (int m = 0; m < 2; m++) {
            const float* rbp = ldsw + buf * 1024 + (m * 16 + col) * 32;
            const int sp0 = (q * 2) ^ c7;
            *(float4*)&xr[m][0] = *(const float4*)(rbp + sp0 * 4);
            *(float4*)&xr[m][4] = *(const float4*)(rbp + (sp0 ^ 1) * 4);
        }

        // prefetch next step (skipped on last iter -- compile-time)
        if (s + 1 < KSTEPS) STAGE(buf ^ 1, s + 1);
        __builtin_amdgcn_sched_barrier(0);

        bf16x8 ah[2], al[2];
        split8(xr[0], ah[0], al[0]);
        split8(xr[1], ah[1], al[1]);
#pragma unroll
        for (int m = 0; m < 2; m++)
#pragma unroll
            for (int t = 0; t < 4; t++) {
                acc[m][t] = __builtin_amdgcn_mfma_f32_16x16x32_bf16(ah[m], bh[t], acc[m][t], 0, 0, 0);
                acc[m][t] = __builtin_amdgcn_mfma_f32_16x16x32_bf16(ah[m], bl[t], acc[m][t], 0, 0, 0);
                acc[m][t] = __builtin_amdgcn_mfma_f32_16x16x32_bf16(al[m], bh[t], acc[m][t], 0, 0, 0);
            }
    }

    // ---- atomic-free tail: cross-wave K reduction in LDS ----
    asm volatile("s_waitcnt vmcnt(0)" ::: "memory");   // all LDS-DMA landed (alias safety)
    __builtin_amdgcn_sched_barrier(0);

    // C/D: row_local = m*16 + q*4 + r, exp = t*16 + col (m89-verified mapping)
#pragma unroll
    for (int m = 0; m < 2; m++)
#pragma unroll
        for (int t = 0; t < 4; t++)
#pragma unroll
            for (int r = 0; r < 4; r++)
                ldsx[wv * 2048 + (m * 16 + q * 4 + r) * 64 + t * 16 + col] = acc[m][t][r];

    __syncthreads();

    // 256 threads x 8 values: sum the 4 wave-partials, store coalesced.
    const f32x4* lp = (const f32x4*)ldsx;   // wave region stride = 512 f32x4
    const f32x4 s0 = lp[tid * 2]     + lp[512 + tid * 2]     + lp[1024 + tid * 2]     + lp[1536 + tid * 2];
    const f32x4 s1 = lp[tid * 2 + 1] + lp[512 + tid * 2 + 1] + lp[1024 + tid * 2 + 1] + lp[1536 + tid * 2 + 1];
    float* po = part + (size_t)kh * NROWS * NEXP + (size_t)r0 * NEXP + tid * 8;
    *(f32x4*)po       = s0;
    *(f32x4*)(po + 4) = s1;
}

// One wave per row: sum 8 split-K partials, sigmoid, +bias, top-2 (tie ->
// lower index), normalize. Kernel boundary provides cross-XCD visibility of
// part (plain stores -> plain loads, verified pattern R0/R8).
// out: [weights 2N][indices-as-float 2N][scores 64N]
__global__ __launch_bounds__(256) void gate_topk_kernel(
    const float* __restrict__ part, const float* __restrict__ bias,
    float* __restrict__ out)
{
    const int tid = threadIdx.x;
    const int e   = tid & 63;
    const int row = blockIdx.x * 4 + (tid >> 6);
    const size_t idx = (size_t)row * NEXP + e;

    const float be = bias[e];           // issue before partial loads
    float logit = 0.f;
#pragma unroll
    for (int s = 0; s < KSPLIT; s++)
        logit += part[(size_t)s * NROWS * NEXP + idx];
    const float score = 1.0f / (1.0f + expf(-logit));
    out[(size_t)4 * NROWS + idx] = score;           // scores

    const float biased = score + be;

    float v = biased; int bi = e;
#pragma unroll
    for (int off = 32; off; off >>= 1) {
        const float ov = __shfl_xor(v, off);
        const int   oi = __shfl_xor(bi, off);
        if (ov > v || (ov == v && oi < bi)) { v = ov; bi = oi; }
    }
    const int i1 = bi;

    float v2 = (e == i1) ? -INFINITY : biased;
    int bi2 = e;
#pragma unroll
    for (int off = 32; off; off >>= 1) {
        const float ov = __shfl_xor(v2, off);
        const int   oi = __shfl_xor(bi2, off);
        if (ov > v2 || (ov == v2 && oi < bi2)) { v2 = ov; bi2 = oi; }
    }
    const int i2 = bi2;

    const float s1 = __shfl(score, i1);
    const float s2 = __shfl(score, i2);
    if (e == 0) {
        const float inv = 1.0f / (s1 + s2);
        out[(size_t)row * 2 + 0] = s1 * inv;
        out[(size_t)row * 2 + 1] = s2 * inv;
        out[(size_t)2 * NROWS + row * 2 + 0] = (float)i1;
        out[(size_t)2 * NROWS + row * 2 + 1] = (float)i2;
    }
}

extern "C" void kernel_launch(void* const* d_in, const int* in_sizes, int n_in,
                              void* d_out, int out_size, void* d_ws, size_t ws_size,
                              hipStream_t stream)
{
    const float* x    = (const float*)d_in[0];
    const float* w    = (const float*)d_in[1];
    const float* bias = (const float*)d_in[2];
    float* out  = (float*)d_out;

    float* part = (float*)d_ws;                                 // 8 x 2 MB
    const size_t part_bytes = (size_t)KSPLIT * NROWS * NEXP * 4;
    unsigned short* whi = (unsigned short*)((char*)d_ws + part_bytes);  // 512 KB
    unsigned short* wlo = whi + (size_t)NEXP * DDIM;                    // 512 KB

    wfrag_kernel<<<DDIM / 32, 256, 0, stream>>>(w, whi, wlo);
    dim3 g1(NROWS / 32, KSPLIT);                                // (256, 8) = 2048 blocks
    gemm_partial_kernel<<<g1, 256, 0, stream>>>(x, whi, wlo, part);
    gate_topk_kernel<<<NROWS / 4, 256, 0, stream>>>(part, bias, out);
}